// Round 18
// baseline (114.937 us; speedup 1.0000x reference)
//
#include <hip/hip_runtime.h>
#include <cmath>

#define NPIX 16384
#define NATOM 1024
#define DIM 64
#define SPAR 8

// ---------------------------------------------------------------------------
// Fused pre-pass, grid-partitioned (1344 blocks) — unchanged (R9-verified):
//   [0,256):    G 64x64 tile = D^T D + 1e-4 I, fp64 acc; Gd diag
//   [256,320):  Dt transpose
//   [320,1344): HB 128n x 128k tile (fp32, 8x8/thread)
// ---------------------------------------------------------------------------
__global__ __launch_bounds__(256) void k_pre(const float* __restrict__ X,
                                             const float* __restrict__ D,
                                             float* __restrict__ G,
                                             float* __restrict__ Dt,
                                             float* __restrict__ Gd,
                                             float* __restrict__ HB) {
  __shared__ float smem[2 * DIM * 128];  // 64 KiB
  const int b = blockIdx.x;
  if (b < 256) {
    const int i0 = (b >> 4) * 64, j0 = (b & 15) * 64;
    float(*sA)[65] = (float(*)[65])smem;
    float(*sB)[65] = (float(*)[65])(smem + DIM * 65);
    for (int t = threadIdx.x; t < DIM * 16; t += 256) {
      int d = t >> 4, c4 = (t & 15) * 4;
      *reinterpret_cast<float4*>(&sA[d][c4]) =
          *reinterpret_cast<const float4*>(&D[(size_t)d * NATOM + i0 + c4]);
      *reinterpret_cast<float4*>(&sB[d][c4]) =
          *reinterpret_cast<const float4*>(&D[(size_t)d * NATOM + j0 + c4]);
    }
    __syncthreads();
    const int ty = (threadIdx.x >> 4) * 4;
    const int tx = (threadIdx.x & 15) * 4;
    double acc[4][4];
#pragma unroll
    for (int ii = 0; ii < 4; ++ii)
#pragma unroll
      for (int jj = 0; jj < 4; ++jj) acc[ii][jj] = 0.0;
    for (int d = 0; d < DIM; ++d) {
      float a[4], bb[4];
#pragma unroll
      for (int ii = 0; ii < 4; ++ii) a[ii] = sA[d][ty + ii];
#pragma unroll
      for (int jj = 0; jj < 4; ++jj) bb[jj] = sB[d][tx + jj];
#pragma unroll
      for (int ii = 0; ii < 4; ++ii)
#pragma unroll
        for (int jj = 0; jj < 4; ++jj)
          acc[ii][jj] += (double)a[ii] * (double)bb[jj];
    }
#pragma unroll
    for (int ii = 0; ii < 4; ++ii)
#pragma unroll
      for (int jj = 0; jj < 4; ++jj) {
        const int k1 = i0 + ty + ii, k2 = j0 + tx + jj;
        float g = (float)acc[ii][jj];
        if (k1 == k2) {
          g += 1e-4f;
          Gd[k1] = g;
        }
        G[(size_t)k1 * NATOM + k2] = g;
      }
  } else if (b < 320) {
    const int base = (b - 256) * 1024 + threadIdx.x * 4;
    float4 v = *reinterpret_cast<const float4*>(&D[base]);
    const float vv[4] = {v.x, v.y, v.z, v.w};
#pragma unroll
    for (int e = 0; e < 4; ++e) {
      int idx = base + e;
      Dt[(size_t)(idx & (NATOM - 1)) * DIM + (idx >> 10)] = vv[e];
    }
  } else {
    const int bx = b - 320;
    const int n0 = (bx & 127) * 128, k0 = (bx >> 7) * 128;
    float(*sX)[128] = (float(*)[128])smem;
    float(*sD)[128] = (float(*)[128])(smem + DIM * 128);
    for (int i = threadIdx.x; i < DIM * 32; i += 256) {
      int d = i >> 5, c4 = (i & 31) * 4;
      *reinterpret_cast<float4*>(&sX[d][c4]) =
          *reinterpret_cast<const float4*>(&X[(size_t)d * NPIX + n0 + c4]);
      *reinterpret_cast<float4*>(&sD[d][c4]) =
          *reinterpret_cast<const float4*>(&D[(size_t)d * NATOM + k0 + c4]);
    }
    __syncthreads();
    const int nl = (threadIdx.x & 15) * 8;
    const int kl = (threadIdx.x >> 4) * 8;
    float acc[8][8];
#pragma unroll
    for (int i = 0; i < 8; ++i)
#pragma unroll
      for (int j = 0; j < 8; ++j) acc[i][j] = 0.f;
#pragma unroll 4
    for (int d = 0; d < DIM; ++d) {
      float xv[8], dv[8];
      *reinterpret_cast<float4*>(&xv[0]) = *reinterpret_cast<float4*>(&sX[d][nl]);
      *reinterpret_cast<float4*>(&xv[4]) = *reinterpret_cast<float4*>(&sX[d][nl + 4]);
      *reinterpret_cast<float4*>(&dv[0]) = *reinterpret_cast<float4*>(&sD[d][kl]);
      *reinterpret_cast<float4*>(&dv[4]) = *reinterpret_cast<float4*>(&sD[d][kl + 4]);
#pragma unroll
      for (int i = 0; i < 8; ++i)
#pragma unroll
        for (int j = 0; j < 8; ++j) acc[i][j] = fmaf(xv[i], dv[j], acc[i][j]);
    }
#pragma unroll
    for (int i = 0; i < 8; ++i)
#pragma unroll
      for (int j = 0; j < 2; ++j)
        *reinterpret_cast<float4*>(
            &HB[(size_t)(n0 + nl + i) * NATOM + k0 + kl + j * 4]) =
            *reinterpret_cast<float4*>(&acc[i][j * 4]);
  }
}

// ---------------------------------------------------------------------------
// DPP wave64 max-reduce (VALU latency, no LDS). HW-verified (rounds 6-17).
// ---------------------------------------------------------------------------
template <int CTRL>
__device__ __forceinline__ float dpp_fmax(float x) {
  int s = __builtin_amdgcn_update_dpp(__float_as_int(x), __float_as_int(x),
                                      CTRL, 0xf, 0xf, false);
  return fmaxf(x, __int_as_float(s));
}
__device__ __forceinline__ float wave_max_bcast(float x) {
  x = dpp_fmax<0x111>(x);  // row_shr:1
  x = dpp_fmax<0x112>(x);  // row_shr:2
  x = dpp_fmax<0x114>(x);  // row_shr:4
  x = dpp_fmax<0x118>(x);  // row_shr:8
  x = dpp_fmax<0x142>(x);  // row_bcast:15
  x = dpp_fmax<0x143>(x);  // row_bcast:31
  return __int_as_float(__builtin_amdgcn_readlane(__float_as_int(x), 63));
}

// force a wave-uniform fp32 value into SGPR allocation (identity on values)
__device__ __forceinline__ float sgprf(float x) {
  return __int_as_float(__builtin_amdgcn_readfirstlane(__float_as_int(x)));
}

// ---------------------------------------------------------------------------
// Batched OMP, Batch-OMP residual recurrence, TWO WAVES PER PIXEL
// (128-thread block). Wave w owns atoms [w*512, w*512+512); lane owns
// k = w*512 + lane*8 + j, j=0..7. Per-wave state ~90 true regs (h 8 +
// wr 56 + transients) -> high occupancy headroom.
// Per step: local DPP argmax on own half; ONE barrier (parity-LDS combine:
// exact max, tie -> min index == np.argmax, R11-verified); scalar Cholesky
// column + y_s DUPLICATED in both waves (identical uniform math via sgprf —
// no publish barrier); wr-build + h-update on own half (R15 recurrence).
// Final backward solve duplicated once post-loop. NaN-poison by owner.
// All per-atom fp chains bit-identical to the passing R15/R16 kernels.
// ---------------------------------------------------------------------------
__global__ __launch_bounds__(128, 3) void k_omp2(const float* __restrict__ HB,
                                                 const float* __restrict__ Dt,
                                                 const float* __restrict__ G,
                                                 const float* __restrict__ Gd,
                                                 float* __restrict__ out) {
  const int lane = threadIdx.x & 63;
  const int wave = threadIdx.x >> 6;
  const int kbase = wave * 512 + lane * 8;
  const int n = __builtin_amdgcn_readfirstlane(blockIdx.x);

  __shared__ float sM[2][2];
  __shared__ int sC[2][2];

  float h[8];  // residual correlations for own half; updated in place
#pragma unroll
  for (int q = 0; q < 2; ++q) {
    float4 v = *reinterpret_cast<const float4*>(
        &HB[(size_t)n * NATOM + kbase + q * 4]);
    h[q * 4 + 0] = v.x; h[q * 4 + 1] = v.y;
    h[q * 4 + 2] = v.z; h[q * 4 + 3] = v.w;
  }
#pragma unroll
  for (int j = 0; j < 8; ++j) asm volatile("" : "+v"(h[j]));

  int selI[SPAR];           // wave-uniform -> SGPRs
  float wr[SPAR - 1][8];    // wr[t][j] = (L^{-1} G_I)[t][kbase+j], pinned
  float Lm[SPAR][SPAR], invL[SPAR], ysel[SPAR];  // uniform -> SGPR via sgprf

#pragma unroll 8
  for (int s = 0; s < SPAR; ++s) {
    // ---- local argmax over |h| (NaN-poisoned slots lose) ----
    float ml = fmaxf(fmaxf(fabsf(h[0]), fabsf(h[1])), fmaxf(fabsf(h[2]), fabsf(h[3])));
    float mh = fmaxf(fmaxf(fabsf(h[4]), fabsf(h[5])), fmaxf(fabsf(h[6]), fabsf(h[7])));
    const float Mw = wave_max_bcast(fmaxf(ml, mh));
    // in-lane first match: 2 parallel descending chains + umin
    unsigned c0 = NATOM, c1 = NATOM;
#pragma unroll
    for (int j = 3; j >= 0; --j) {
      c0 = (fabsf(h[j]) == Mw) ? (unsigned)(kbase + j) : c0;
      c1 = (fabsf(h[4 + j]) == Mw) ? (unsigned)(kbase + 4 + j) : c1;
    }
    unsigned cand = c0 < c1 ? c0 : c1;
    unsigned long long bal = __ballot(cand != (unsigned)NATOM);
    const int fl = __ffsll(bal) - 1;  // >=0: local max always has a match
    const int cw = __builtin_amdgcn_readlane((int)cand, fl);
    // ---- cross-wave combine (one barrier; parity double-buffer) ----
    if (lane == 0) {
      sM[s & 1][wave] = Mw;
      sC[s & 1][wave] = cw;
    }
    __syncthreads();
    const float M0 = sM[s & 1][0], M1 = sM[s & 1][1];
    const int cc0 = sC[s & 1][0], cc1 = sC[s & 1][1];
    int bkv;
    if (M0 > M1) bkv = cc0;
    else if (M1 > M0) bkv = cc1;
    else bkv = cc0 < cc1 ? cc0 : cc1;
    const int bk = __builtin_amdgcn_readfirstlane(bkv);
    selI[s] = bk;

    // poison the selected slot in its owning wave/lane (NaN semantics)
    if ((bk >> 9) == wave && lane == ((bk >> 3) & 63)) {
#pragma unroll
      for (int j = 0; j < 8; ++j)
        if (j == (bk & 7)) h[j] = __builtin_nanf("");
    }

    // issue G-row fetch early; waitcnt lands after the scalar chol below
    float g[8];
    if (s < SPAR - 1) {
#pragma unroll
      for (int q = 0; q < 2; ++q) {
        float4 rv = *reinterpret_cast<const float4*>(
            &G[(size_t)bk * NATOM + kbase + q * 4]);
        g[q * 4 + 0] = rv.x; g[q * 4 + 1] = rv.y;
        g[q * 4 + 2] = rv.z; g[q * 4 + 3] = rv.w;
      }
    }

    // ---- scalar Cholesky column + y_s (duplicated; identical uniform) ----
    const float hbs = HB[(size_t)n * NATOM + bk];  // uniform scalar load
    const float diag = Gd[bk];
    float colv[SPAR];
#pragma unroll
    for (int i = 0; i < SPAR; ++i)
      if (i < s) colv[i] = G[(size_t)selI[i] * NATOM + bk];
    float w[SPAR];
    float sq = 0.f;
#pragma unroll
    for (int i = 0; i < SPAR; ++i)
      if (i < s) {
        float a = colv[i];
#pragma unroll
        for (int t = 0; t < SPAR; ++t)
          if (t < i) a = fmaf(-Lm[i][t], w[t], a);
        w[i] = a * invL[i];
        sq += w[i] * w[i];
        Lm[s][i] = sgprf(w[i]);  // uniform -> SGPR
      }
    float cc = diag - sq;
    if (cc < 1e-6f) cc = 1e-6f;  // jnp.clip(..., CHOL_EPS)
    invL[s] = sgprf(1.0f / sqrtf(cc));
    {
      float a = hbs;
#pragma unroll
      for (int t = 0; t < SPAR; ++t)
        if (t < s) a = fmaf(-Lm[s][t], ysel[t], a);
      ysel[s] = sgprf(a * invL[s]);
    }

    // ---- wr_s = (g - sum_t Lm[s][t]*wr_t)*invL[s]; h -= y_s*wr_s ----
    if (s < SPAR - 1) {
#pragma unroll
      for (int j = 0; j < 8; ++j) {
        float a = g[j];
#pragma unroll
        for (int t = 0; t < SPAR - 1; ++t)
          if (t < s) a = fmaf(-Lm[s][t], wr[t][j], a);
        float v = a * invL[s];
        wr[s][j] = v;
        h[j] = fmaf(-ysel[s], v, h[j]);
      }
#pragma unroll
      for (int j = 0; j < 8; ++j) asm volatile("" : "+v"(wr[s][j]));
    }
  }

  // ---- final backward solve L^T c = y (duplicated; op-identical) ----
  float coefF[SPAR];
#pragma unroll
  for (int i = SPAR - 1; i >= 0; --i) {
    float a = ysel[i];
#pragma unroll
    for (int t = 0; t < SPAR; ++t)
      if (t > i) a = fmaf(-Lm[t][i], coefF[t], a);
    coefF[i] = a * invL[i];
  }

  // ---- outputs: wave 0 -> recon [n][64]; wave 1 -> I and coeffs ----
  if (wave == 0) {
    double r = 0.0;
#pragma unroll
    for (int i = 0; i < SPAR; ++i)
      r += (double)coefF[i] * (double)Dt[(size_t)selI[i] * DIM + lane];
    out[(size_t)n * DIM + lane] = (float)r;
  } else {
    float fi = 0.f, fc = 0.f;
#pragma unroll
    for (int i = 0; i < SPAR; ++i)
      if (lane == i) { fi = (float)selI[i]; fc = coefF[i]; }
    if (lane < SPAR) {
      out[(size_t)NPIX * DIM + (size_t)n * SPAR + lane] = fi;
      out[(size_t)NPIX * DIM + (size_t)NPIX * SPAR + (size_t)n * SPAR + lane] = fc;
    }
  }
}

// ---------------------------------------------------------------------------
// Fallback single-wave OMP (tiny-workspace path; R10 kernel). Unchanged.
// ---------------------------------------------------------------------------
__global__ __launch_bounds__(64) void k_omp_fb(const float* __restrict__ X,
                                               const float* __restrict__ D,
                                               const float* __restrict__ G,
                                               const float* __restrict__ Gd,
                                               float* __restrict__ out) {
  const int lane = threadIdx.x & 63;
  const int lane16 = lane * 16;
  const int n = __builtin_amdgcn_readfirstlane(blockIdx.x);

  float hb[16];
  {
    double a[16];
#pragma unroll
    for (int j = 0; j < 16; ++j) a[j] = 0.0;
    for (int d = 0; d < DIM; ++d) {
      float xd = X[(size_t)d * NPIX + n];
#pragma unroll
      for (int j = 0; j < 16; ++j)
        a[j] += (double)xd * (double)D[(size_t)d * NATOM + lane16 + j];
    }
#pragma unroll
    for (int j = 0; j < 16; ++j) hb[j] = (float)a[j];
  }
#pragma unroll
  for (int j = 0; j < 16; ++j) asm volatile("" : "+v"(hb[j]));

  int selI[SPAR];
  float rows[SPAR - 1][16];
  float Lm[SPAR][SPAR], invL[SPAR], ysel[SPAR], coefF[SPAR];

#pragma unroll 8
  for (int s = 0; s < SPAR; ++s) {
    float h[16];
#pragma unroll
    for (int j = 0; j < 16; ++j) {
      float hv = hb[j];
#pragma unroll
      for (int i = 0; i < SPAR - 1; ++i)
        if (i < s) hv = fmaf(-coefF[i], rows[i][j], hv);
      h[j] = hv;
    }
    float m0 = fmaxf(fmaxf(fmaxf(fabsf(h[0]), fabsf(h[1])), fabsf(h[2])), fabsf(h[3]));
    float m1 = fmaxf(fmaxf(fmaxf(fabsf(h[4]), fabsf(h[5])), fabsf(h[6])), fabsf(h[7]));
    float m2 = fmaxf(fmaxf(fmaxf(fabsf(h[8]), fabsf(h[9])), fabsf(h[10])), fabsf(h[11]));
    float m3 = fmaxf(fmaxf(fmaxf(fabsf(h[12]), fabsf(h[13])), fabsf(h[14])), fabsf(h[15]));
    const float M = wave_max_bcast(fmaxf(fmaxf(m0, m1), fmaxf(m2, m3)));
    unsigned cand = NATOM;
#pragma unroll
    for (int j = 15; j >= 0; --j)
      cand = (fabsf(h[j]) == M) ? (unsigned)(lane16 + j) : cand;
    unsigned long long bal = __ballot(cand != (unsigned)NATOM);
    const int fl = __ffsll(bal) - 1;
    const int bk = __builtin_amdgcn_readlane((int)cand, fl);
    selI[s] = bk;
    const int bl = bk >> 4, bj = bk & 15;

    float v = 0.f;
#pragma unroll
    for (int j = 0; j < 16; ++j)
      if (j == bj) v = hb[j];
    const float hbs =
        __int_as_float(__builtin_amdgcn_readlane(__float_as_int(v), bl));

#pragma unroll
    for (int j = 0; j < 16; ++j)
      if (j == bj && lane == bl) hb[j] = __builtin_nanf("");

    if (s < SPAR - 1) {
#pragma unroll
      for (int q = 0; q < 4; ++q) {
        float4 rv = *reinterpret_cast<const float4*>(
            &G[(size_t)bk * NATOM + lane16 + q * 4]);
        rows[s][q * 4 + 0] = rv.x; rows[s][q * 4 + 1] = rv.y;
        rows[s][q * 4 + 2] = rv.z; rows[s][q * 4 + 3] = rv.w;
      }
    }

    const float diag = Gd[bk];
    float w[SPAR];
    float sq = 0.f;
#pragma unroll
    for (int i = 0; i < SPAR; ++i)
      if (i < s) {
        float a = G[(size_t)selI[i] * NATOM + bk];
#pragma unroll
        for (int t = 0; t < SPAR; ++t)
          if (t < i) a = fmaf(-Lm[i][t], w[t], a);
        w[i] = a * invL[i];
        sq += w[i] * w[i];
        Lm[s][i] = w[i];
      }
    float cc = diag - sq;
    if (cc < 1e-6f) cc = 1e-6f;
    invL[s] = 1.0f / sqrtf(cc);
    {
      float a = hbs;
#pragma unroll
      for (int t = 0; t < SPAR; ++t)
        if (t < s) a = fmaf(-Lm[s][t], ysel[t], a);
      ysel[s] = a * invL[s];
    }
#pragma unroll
    for (int i = SPAR - 1; i >= 0; --i)
      if (i <= s) {
        float a = ysel[i];
#pragma unroll
        for (int t = 0; t < SPAR; ++t)
          if (t > i && t <= s) a = fmaf(-Lm[t][i], coefF[t], a);
        coefF[i] = a * invL[i];
      }
    if (s < SPAR - 1) {
#pragma unroll
      for (int j = 0; j < 16; ++j) asm volatile("" : "+v"(rows[s][j]));
    }
  }

  double r = 0.0;
#pragma unroll
  for (int i = 0; i < SPAR; ++i)
    r += (double)coefF[i] * (double)D[(size_t)lane * NATOM + selI[i]];
  out[(size_t)n * DIM + lane] = (float)r;

  float fi = 0.f, fc = 0.f;
#pragma unroll
  for (int i = 0; i < SPAR; ++i)
    if (lane == i) { fi = (float)selI[i]; fc = coefF[i]; }
  if (lane < SPAR) {
    out[(size_t)NPIX * DIM + (size_t)n * SPAR + lane] = fi;
    out[(size_t)NPIX * DIM + (size_t)NPIX * SPAR + (size_t)n * SPAR + lane] = fc;
  }
}

__global__ __launch_bounds__(256) void k_gram(const float* __restrict__ D,
                                              float* __restrict__ G,
                                              float* __restrict__ Gd) {
  int k1 = blockIdx.x;
  __shared__ float d1[DIM];
  if (threadIdx.x < DIM) d1[threadIdx.x] = D[(size_t)threadIdx.x * NATOM + k1];
  __syncthreads();
  for (int k2 = threadIdx.x; k2 < NATOM; k2 += 256) {
    double acc = 0.0;
#pragma unroll
    for (int d = 0; d < DIM; ++d)
      acc += (double)d1[d] * (double)D[(size_t)d * NATOM + k2];
    float g = (float)acc;
    if (k2 == k1) {
      g += 1e-4f;
      Gd[k1] = g;
    }
    G[(size_t)k1 * NATOM + k2] = g;
  }
}

extern "C" void kernel_launch(void* const* d_in, const int* in_sizes, int n_in,
                              void* d_out, int out_size, void* d_ws,
                              size_t ws_size, hipStream_t stream) {
  const float* X = (const float*)d_in[0];  // [64, 16384]
  const float* D = (const float*)d_in[1];  // [64, 1024]
  float* out = (float*)d_out;              // [recon | I | coeffs] as fp32
  float* G = (float*)d_ws;                 // 4 MB
  float* Dt = G + (size_t)NATOM * NATOM;   // 256 KB
  float* Gd = Dt + (size_t)NATOM * DIM;    // 4 KB
  float* HB = Gd + NATOM;                  // 64 MB
  const size_t needFull =
      ((size_t)NATOM * NATOM + (size_t)NATOM * DIM + NATOM +
       (size_t)NPIX * NATOM) * sizeof(float);

  if (ws_size >= needFull) {
    k_pre<<<dim3(1344), dim3(256), 0, stream>>>(X, D, G, Dt, Gd, HB);
    k_omp2<<<dim3(NPIX), dim3(128), 0, stream>>>(HB, Dt, G, Gd, out);
  } else {
    k_gram<<<dim3(NATOM), dim3(256), 0, stream>>>(D, G, Gd);
    k_omp_fb<<<dim3(NPIX), dim3(64), 0, stream>>>(X, D, G, Gd, out);
  }
}

// Round 19
// 101.492 us; speedup vs baseline: 1.1325x; 1.1325x over previous
//
#include <hip/hip_runtime.h>
#include <cmath>

#define NPIX 16384
#define NATOM 1024
#define DIM 64
#define SPAR 8

// ---------------------------------------------------------------------------
// Fused pre-pass, grid-partitioned (1344 blocks) — unchanged (R9-verified):
//   [0,256):    G 64x64 tile = D^T D + 1e-4 I, fp64 acc; Gd diag
//   [256,320):  Dt transpose
//   [320,1344): HB 128n x 128k tile (fp32, 8x8/thread)
// ---------------------------------------------------------------------------
__global__ __launch_bounds__(256) void k_pre(const float* __restrict__ X,
                                             const float* __restrict__ D,
                                             float* __restrict__ G,
                                             float* __restrict__ Dt,
                                             float* __restrict__ Gd,
                                             float* __restrict__ HB) {
  __shared__ float smem[2 * DIM * 128];  // 64 KiB
  const int b = blockIdx.x;
  if (b < 256) {
    const int i0 = (b >> 4) * 64, j0 = (b & 15) * 64;
    float(*sA)[65] = (float(*)[65])smem;
    float(*sB)[65] = (float(*)[65])(smem + DIM * 65);
    for (int t = threadIdx.x; t < DIM * 16; t += 256) {
      int d = t >> 4, c4 = (t & 15) * 4;
      *reinterpret_cast<float4*>(&sA[d][c4]) =
          *reinterpret_cast<const float4*>(&D[(size_t)d * NATOM + i0 + c4]);
      *reinterpret_cast<float4*>(&sB[d][c4]) =
          *reinterpret_cast<const float4*>(&D[(size_t)d * NATOM + j0 + c4]);
    }
    __syncthreads();
    const int ty = (threadIdx.x >> 4) * 4;
    const int tx = (threadIdx.x & 15) * 4;
    double acc[4][4];
#pragma unroll
    for (int ii = 0; ii < 4; ++ii)
#pragma unroll
      for (int jj = 0; jj < 4; ++jj) acc[ii][jj] = 0.0;
    for (int d = 0; d < DIM; ++d) {
      float a[4], bb[4];
#pragma unroll
      for (int ii = 0; ii < 4; ++ii) a[ii] = sA[d][ty + ii];
#pragma unroll
      for (int jj = 0; jj < 4; ++jj) bb[jj] = sB[d][tx + jj];
#pragma unroll
      for (int ii = 0; ii < 4; ++ii)
#pragma unroll
        for (int jj = 0; jj < 4; ++jj)
          acc[ii][jj] += (double)a[ii] * (double)bb[jj];
    }
#pragma unroll
    for (int ii = 0; ii < 4; ++ii)
#pragma unroll
      for (int jj = 0; jj < 4; ++jj) {
        const int k1 = i0 + ty + ii, k2 = j0 + tx + jj;
        float g = (float)acc[ii][jj];
        if (k1 == k2) {
          g += 1e-4f;
          Gd[k1] = g;
        }
        G[(size_t)k1 * NATOM + k2] = g;
      }
  } else if (b < 320) {
    const int base = (b - 256) * 1024 + threadIdx.x * 4;
    float4 v = *reinterpret_cast<const float4*>(&D[base]);
    const float vv[4] = {v.x, v.y, v.z, v.w};
#pragma unroll
    for (int e = 0; e < 4; ++e) {
      int idx = base + e;
      Dt[(size_t)(idx & (NATOM - 1)) * DIM + (idx >> 10)] = vv[e];
    }
  } else {
    const int bx = b - 320;
    const int n0 = (bx & 127) * 128, k0 = (bx >> 7) * 128;
    float(*sX)[128] = (float(*)[128])smem;
    float(*sD)[128] = (float(*)[128])(smem + DIM * 128);
    for (int i = threadIdx.x; i < DIM * 32; i += 256) {
      int d = i >> 5, c4 = (i & 31) * 4;
      *reinterpret_cast<float4*>(&sX[d][c4]) =
          *reinterpret_cast<const float4*>(&X[(size_t)d * NPIX + n0 + c4]);
      *reinterpret_cast<float4*>(&sD[d][c4]) =
          *reinterpret_cast<const float4*>(&D[(size_t)d * NATOM + k0 + c4]);
    }
    __syncthreads();
    const int nl = (threadIdx.x & 15) * 8;
    const int kl = (threadIdx.x >> 4) * 8;
    float acc[8][8];
#pragma unroll
    for (int i = 0; i < 8; ++i)
#pragma unroll
      for (int j = 0; j < 8; ++j) acc[i][j] = 0.f;
#pragma unroll 4
    for (int d = 0; d < DIM; ++d) {
      float xv[8], dv[8];
      *reinterpret_cast<float4*>(&xv[0]) = *reinterpret_cast<float4*>(&sX[d][nl]);
      *reinterpret_cast<float4*>(&xv[4]) = *reinterpret_cast<float4*>(&sX[d][nl + 4]);
      *reinterpret_cast<float4*>(&dv[0]) = *reinterpret_cast<float4*>(&sD[d][kl]);
      *reinterpret_cast<float4*>(&dv[4]) = *reinterpret_cast<float4*>(&sD[d][kl + 4]);
#pragma unroll
      for (int i = 0; i < 8; ++i)
#pragma unroll
        for (int j = 0; j < 8; ++j) acc[i][j] = fmaf(xv[i], dv[j], acc[i][j]);
    }
#pragma unroll
    for (int i = 0; i < 8; ++i)
#pragma unroll
      for (int j = 0; j < 2; ++j)
        *reinterpret_cast<float4*>(
            &HB[(size_t)(n0 + nl + i) * NATOM + k0 + kl + j * 4]) =
            *reinterpret_cast<float4*>(&acc[i][j * 4]);
  }
}

// ---------------------------------------------------------------------------
// DPP wave64 max-reduce (VALU latency, no LDS). HW-verified (rounds 6-18).
// ---------------------------------------------------------------------------
template <int CTRL>
__device__ __forceinline__ float dpp_fmax(float x) {
  int s = __builtin_amdgcn_update_dpp(__float_as_int(x), __float_as_int(x),
                                      CTRL, 0xf, 0xf, false);
  return fmaxf(x, __int_as_float(s));
}
__device__ __forceinline__ float wave_max_bcast(float x) {
  x = dpp_fmax<0x111>(x);  // row_shr:1
  x = dpp_fmax<0x112>(x);  // row_shr:2
  x = dpp_fmax<0x114>(x);  // row_shr:4
  x = dpp_fmax<0x118>(x);  // row_shr:8
  x = dpp_fmax<0x142>(x);  // row_bcast:15
  x = dpp_fmax<0x143>(x);  // row_bcast:31
  return __int_as_float(__builtin_amdgcn_readlane(__float_as_int(x), 63));
}

// force a wave-uniform fp32 value into SGPR allocation (identity on values)
__device__ __forceinline__ float sgprf(float x) {
  return __int_as_float(__builtin_amdgcn_readfirstlane(__float_as_int(x)));
}

// ---------------------------------------------------------------------------
// Batched OMP via Batch-OMP residual recurrence (R15/R16-verified math).
// ONE WAVE PER PIXEL. Lane owns atoms k = lane*16+j.
// __launch_bounds__(64, 2): VGPR budget 256 so the wr[7][16]+h[16] arrays
// live in TRUE VGPRs (no AGPR shunt, no v_accvgpr_read/write traffic —
// R16's (64,3) bound forced them into AGPRs at no occupancy gain).
// Asm pins removed: wr is COMPUTED (not loaded) — no remat risk; pins only
// constrained the allocator. Solver state (Lm/invL/ysel) in SGPRs (sgprf).
// Argmax: exact f32 DPP wave-max; 4 parallel descending-j chains + umin
// tree; ballot+ffs (== np.argmax first occurrence). NaN-poison h.
// hbs/diag/chol-column via wave-uniform scalar loads. Numerics bit-identical
// to the passing R16 kernel (register placement changes no fp op).
// ---------------------------------------------------------------------------
template <bool DTW>
__global__ __launch_bounds__(64, 2) void k_omp(const float* __restrict__ HB,
                                               const float* __restrict__ Dt,
                                               const float* __restrict__ D,
                                               const float* __restrict__ G,
                                               const float* __restrict__ Gd,
                                               float* __restrict__ out) {
  const int lane = threadIdx.x & 63;
  const int lane16 = lane * 16;
  const int n = __builtin_amdgcn_readfirstlane(blockIdx.x);

  float h[16];  // residual correlations; starts as h_bar, updated in place
#pragma unroll
  for (int q = 0; q < 4; ++q) {
    float4 v = *reinterpret_cast<const float4*>(
        &HB[(size_t)n * NATOM + lane16 + q * 4]);
    h[q * 4 + 0] = v.x; h[q * 4 + 1] = v.y;
    h[q * 4 + 2] = v.z; h[q * 4 + 3] = v.w;
  }

  int selI[SPAR];            // wave-uniform -> SGPRs
  float wr[SPAR - 1][16];    // wr[t][j] = (L^{-1} G_I)[t][lane16+j]
  float Lm[SPAR][SPAR], invL[SPAR], ysel[SPAR];  // uniform -> SGPR via sgprf

#pragma unroll 8
  for (int s = 0; s < SPAR; ++s) {
    // ---- argmax over |h| (NaN-poisoned slots lose: fmaxf ignores NaN) ----
    float m0 = fmaxf(fmaxf(fabsf(h[0]), fabsf(h[1])), fabsf(h[2]));
    float m1 = fmaxf(fmaxf(fabsf(h[3]), fabsf(h[4])), fabsf(h[5]));
    float m2 = fmaxf(fmaxf(fabsf(h[6]), fabsf(h[7])), fabsf(h[8]));
    float m3 = fmaxf(fmaxf(fabsf(h[9]), fabsf(h[10])), fabsf(h[11]));
    float m4 = fmaxf(fmaxf(fabsf(h[12]), fabsf(h[13])), fabsf(h[14]));
    float m5 = fabsf(h[15]);
    const float M = wave_max_bcast(
        fmaxf(fmaxf(fmaxf(m0, m1), m2), fmaxf(fmaxf(m3, m4), m5)));
    // ---- in-lane first match: 4 parallel descending chains + umin tree ----
    unsigned c0 = NATOM, c1 = NATOM, c2 = NATOM, c3 = NATOM;
#pragma unroll
    for (int j = 3; j >= 0; --j) {
      c0 = (fabsf(h[j]) == M) ? (unsigned)(lane16 + j) : c0;
      c1 = (fabsf(h[4 + j]) == M) ? (unsigned)(lane16 + 4 + j) : c1;
      c2 = (fabsf(h[8 + j]) == M) ? (unsigned)(lane16 + 8 + j) : c2;
      c3 = (fabsf(h[12 + j]) == M) ? (unsigned)(lane16 + 12 + j) : c3;
    }
    unsigned ca = c0 < c1 ? c0 : c1;
    unsigned cb = c2 < c3 ? c2 : c3;
    unsigned cand = ca < cb ? ca : cb;
    unsigned long long bal = __ballot(cand != (unsigned)NATOM);
    const int fl = __ffsll(bal) - 1;
    const int bk = __builtin_amdgcn_readlane((int)cand, fl);  // wave-uniform
    selI[s] = bk;
    const int bl = bk >> 4, bj = bk & 15;

    // poison the selected slot: loses every future argmax (NaN semantics)
#pragma unroll
    for (int j = 0; j < 16; ++j)
      if (j == bj && lane == bl) h[j] = __builtin_nanf("");

    // issue G-row fetch early; its waitcnt lands after the scalar chol below
    float g[16];
    if (s < SPAR - 1) {
#pragma unroll
      for (int q = 0; q < 4; ++q) {
        float4 rv = *reinterpret_cast<const float4*>(
            &G[(size_t)bk * NATOM + lane16 + q * 4]);
        g[q * 4 + 0] = rv.x; g[q * 4 + 1] = rv.y;
        g[q * 4 + 2] = rv.z; g[q * 4 + 3] = rv.w;
      }
    }

    // ---- scalar Cholesky column update (wave-uniform loads & math) ----
    const float hbs = HB[(size_t)n * NATOM + bk];  // uniform scalar load
    const float diag = Gd[bk];
    float colv[SPAR];
#pragma unroll
    for (int i = 0; i < SPAR; ++i)
      if (i < s) colv[i] = G[(size_t)selI[i] * NATOM + bk];
    float w[SPAR];
    float sq = 0.f;
#pragma unroll
    for (int i = 0; i < SPAR; ++i)
      if (i < s) {
        float a = colv[i];
#pragma unroll
        for (int t = 0; t < SPAR; ++t)
          if (t < i) a = fmaf(-Lm[i][t], w[t], a);
        w[i] = a * invL[i];
        sq += w[i] * w[i];
        Lm[s][i] = sgprf(w[i]);  // uniform -> SGPR
      }
    float cc = diag - sq;
    if (cc < 1e-6f) cc = 1e-6f;  // jnp.clip(..., CHOL_EPS)
    invL[s] = sgprf(1.0f / sqrtf(cc));

    // ---- y_s (incremental forward solve; earlier entries stable) ----
    {
      float a = hbs;
#pragma unroll
      for (int t = 0; t < SPAR; ++t)
        if (t < s) a = fmaf(-Lm[s][t], ysel[t], a);
      ysel[s] = sgprf(a * invL[s]);
    }

    // ---- build wr_s = (g - sum_t Lm[s][t]*wr_t) * invL[s]; h -= y_s*wr_s --
    if (s < SPAR - 1) {
#pragma unroll
      for (int j = 0; j < 16; ++j) {
        float a = g[j];
#pragma unroll
        for (int t = 0; t < SPAR - 1; ++t)
          if (t < s) a = fmaf(-Lm[s][t], wr[t][j], a);
        float v = a * invL[s];
        wr[s][j] = v;
        h[j] = fmaf(-ysel[s], v, h[j]);
      }
    }
  }

  // ---- final backward solve L^T c = y (op-identical to prior rounds) ----
  float coefF[SPAR];
#pragma unroll
  for (int i = SPAR - 1; i >= 0; --i) {
    float a = ysel[i];
#pragma unroll
    for (int t = 0; t < SPAR; ++t)
      if (t > i) a = fmaf(-Lm[t][i], coefF[t], a);
    coefF[i] = a * invL[i];
  }

  // ---- outputs: recon [n][64], I [n][8], coeffs [n][8] ----
  double r = 0.0;
#pragma unroll
  for (int i = 0; i < SPAR; ++i) {
    float dv = DTW ? Dt[(size_t)selI[i] * DIM + lane]
                   : D[(size_t)lane * NATOM + selI[i]];
    r += (double)coefF[i] * (double)dv;
  }
  out[(size_t)n * DIM + lane] = (float)r;

  float fi = 0.f, fc = 0.f;
#pragma unroll
  for (int i = 0; i < SPAR; ++i)
    if (lane == i) { fi = (float)selI[i]; fc = coefF[i]; }
  if (lane < SPAR) {
    out[(size_t)NPIX * DIM + (size_t)n * SPAR + lane] = fi;
    out[(size_t)NPIX * DIM + (size_t)NPIX * SPAR + (size_t)n * SPAR + lane] = fc;
  }
}

// ---------------------------------------------------------------------------
// Fallback single-wave OMP (tiny-workspace path; R10 kernel). Unchanged.
// ---------------------------------------------------------------------------
__global__ __launch_bounds__(64) void k_omp_fb(const float* __restrict__ X,
                                               const float* __restrict__ D,
                                               const float* __restrict__ G,
                                               const float* __restrict__ Gd,
                                               float* __restrict__ out) {
  const int lane = threadIdx.x & 63;
  const int lane16 = lane * 16;
  const int n = __builtin_amdgcn_readfirstlane(blockIdx.x);

  float hb[16];
  {
    double a[16];
#pragma unroll
    for (int j = 0; j < 16; ++j) a[j] = 0.0;
    for (int d = 0; d < DIM; ++d) {
      float xd = X[(size_t)d * NPIX + n];
#pragma unroll
      for (int j = 0; j < 16; ++j)
        a[j] += (double)xd * (double)D[(size_t)d * NATOM + lane16 + j];
    }
#pragma unroll
    for (int j = 0; j < 16; ++j) hb[j] = (float)a[j];
  }
#pragma unroll
  for (int j = 0; j < 16; ++j) asm volatile("" : "+v"(hb[j]));

  int selI[SPAR];
  float rows[SPAR - 1][16];
  float Lm[SPAR][SPAR], invL[SPAR], ysel[SPAR], coefF[SPAR];

#pragma unroll 8
  for (int s = 0; s < SPAR; ++s) {
    float h[16];
#pragma unroll
    for (int j = 0; j < 16; ++j) {
      float hv = hb[j];
#pragma unroll
      for (int i = 0; i < SPAR - 1; ++i)
        if (i < s) hv = fmaf(-coefF[i], rows[i][j], hv);
      h[j] = hv;
    }
    float m0 = fmaxf(fmaxf(fmaxf(fabsf(h[0]), fabsf(h[1])), fabsf(h[2])), fabsf(h[3]));
    float m1 = fmaxf(fmaxf(fmaxf(fabsf(h[4]), fabsf(h[5])), fabsf(h[6])), fabsf(h[7]));
    float m2 = fmaxf(fmaxf(fmaxf(fabsf(h[8]), fabsf(h[9])), fabsf(h[10])), fabsf(h[11]));
    float m3 = fmaxf(fmaxf(fmaxf(fabsf(h[12]), fabsf(h[13])), fabsf(h[14])), fabsf(h[15]));
    const float M = wave_max_bcast(fmaxf(fmaxf(m0, m1), fmaxf(m2, m3)));
    unsigned cand = NATOM;
#pragma unroll
    for (int j = 15; j >= 0; --j)
      cand = (fabsf(h[j]) == M) ? (unsigned)(lane16 + j) : cand;
    unsigned long long bal = __ballot(cand != (unsigned)NATOM);
    const int fl = __ffsll(bal) - 1;
    const int bk = __builtin_amdgcn_readlane((int)cand, fl);
    selI[s] = bk;
    const int bl = bk >> 4, bj = bk & 15;

    float v = 0.f;
#pragma unroll
    for (int j = 0; j < 16; ++j)
      if (j == bj) v = hb[j];
    const float hbs =
        __int_as_float(__builtin_amdgcn_readlane(__float_as_int(v), bl));

#pragma unroll
    for (int j = 0; j < 16; ++j)
      if (j == bj && lane == bl) hb[j] = __builtin_nanf("");

    if (s < SPAR - 1) {
#pragma unroll
      for (int q = 0; q < 4; ++q) {
        float4 rv = *reinterpret_cast<const float4*>(
            &G[(size_t)bk * NATOM + lane16 + q * 4]);
        rows[s][q * 4 + 0] = rv.x; rows[s][q * 4 + 1] = rv.y;
        rows[s][q * 4 + 2] = rv.z; rows[s][q * 4 + 3] = rv.w;
      }
    }

    const float diag = Gd[bk];
    float w[SPAR];
    float sq = 0.f;
#pragma unroll
    for (int i = 0; i < SPAR; ++i)
      if (i < s) {
        float a = G[(size_t)selI[i] * NATOM + bk];
#pragma unroll
        for (int t = 0; t < SPAR; ++t)
          if (t < i) a = fmaf(-Lm[i][t], w[t], a);
        w[i] = a * invL[i];
        sq += w[i] * w[i];
        Lm[s][i] = w[i];
      }
    float cc = diag - sq;
    if (cc < 1e-6f) cc = 1e-6f;
    invL[s] = 1.0f / sqrtf(cc);
    {
      float a = hbs;
#pragma unroll
      for (int t = 0; t < SPAR; ++t)
        if (t < s) a = fmaf(-Lm[s][t], ysel[t], a);
      ysel[s] = a * invL[s];
    }
#pragma unroll
    for (int i = SPAR - 1; i >= 0; --i)
      if (i <= s) {
        float a = ysel[i];
#pragma unroll
        for (int t = 0; t < SPAR; ++t)
          if (t > i && t <= s) a = fmaf(-Lm[t][i], coefF[t], a);
        coefF[i] = a * invL[i];
      }
    if (s < SPAR - 1) {
#pragma unroll
      for (int j = 0; j < 16; ++j) asm volatile("" : "+v"(rows[s][j]));
    }
  }

  double r = 0.0;
#pragma unroll
  for (int i = 0; i < SPAR; ++i)
    r += (double)coefF[i] * (double)D[(size_t)lane * NATOM + selI[i]];
  out[(size_t)n * DIM + lane] = (float)r;

  float fi = 0.f, fc = 0.f;
#pragma unroll
  for (int i = 0; i < SPAR; ++i)
    if (lane == i) { fi = (float)selI[i]; fc = coefF[i]; }
  if (lane < SPAR) {
    out[(size_t)NPIX * DIM + (size_t)n * SPAR + lane] = fi;
    out[(size_t)NPIX * DIM + (size_t)NPIX * SPAR + (size_t)n * SPAR + lane] = fc;
  }
}

__global__ __launch_bounds__(256) void k_gram(const float* __restrict__ D,
                                              float* __restrict__ G,
                                              float* __restrict__ Gd) {
  int k1 = blockIdx.x;
  __shared__ float d1[DIM];
  if (threadIdx.x < DIM) d1[threadIdx.x] = D[(size_t)threadIdx.x * NATOM + k1];
  __syncthreads();
  for (int k2 = threadIdx.x; k2 < NATOM; k2 += 256) {
    double acc = 0.0;
#pragma unroll
    for (int d = 0; d < DIM; ++d)
      acc += (double)d1[d] * (double)D[(size_t)d * NATOM + k2];
    float g = (float)acc;
    if (k2 == k1) {
      g += 1e-4f;
      Gd[k1] = g;
    }
    G[(size_t)k1 * NATOM + k2] = g;
  }
}

extern "C" void kernel_launch(void* const* d_in, const int* in_sizes, int n_in,
                              void* d_out, int out_size, void* d_ws,
                              size_t ws_size, hipStream_t stream) {
  const float* X = (const float*)d_in[0];  // [64, 16384]
  const float* D = (const float*)d_in[1];  // [64, 1024]
  float* out = (float*)d_out;              // [recon | I | coeffs] as fp32
  float* G = (float*)d_ws;                 // 4 MB
  float* Dt = G + (size_t)NATOM * NATOM;   // 256 KB
  float* Gd = Dt + (size_t)NATOM * DIM;    // 4 KB
  float* HB = Gd + NATOM;                  // 64 MB
  const size_t needFull =
      ((size_t)NATOM * NATOM + (size_t)NATOM * DIM + NATOM +
       (size_t)NPIX * NATOM) * sizeof(float);

  if (ws_size >= needFull) {
    k_pre<<<dim3(1344), dim3(256), 0, stream>>>(X, D, G, Dt, Gd, HB);
    k_omp<true><<<dim3(NPIX), dim3(64), 0, stream>>>(HB, Dt, nullptr, G, Gd, out);
  } else {
    k_gram<<<dim3(NATOM), dim3(256), 0, stream>>>(D, G, Gd);
    k_omp_fb<<<dim3(NPIX), dim3(64), 0, stream>>>(X, D, G, Gd, out);
  }
}

// Round 20
// 98.816 us; speedup vs baseline: 1.1631x; 1.0271x over previous
//
#include <hip/hip_runtime.h>
#include <cmath>

#define NPIX 16384
#define NATOM 1024
#define DIM 64
#define SPAR 8

// ---------------------------------------------------------------------------
// Fused pre-pass, grid-partitioned (1344 blocks) — unchanged (R9-verified):
//   [0,256):    G 64x64 tile = D^T D + 1e-4 I, fp64 acc; Gd diag
//   [256,320):  Dt transpose
//   [320,1344): HB 128n x 128k tile (fp32, 8x8/thread)
// ---------------------------------------------------------------------------
__global__ __launch_bounds__(256) void k_pre(const float* __restrict__ X,
                                             const float* __restrict__ D,
                                             float* __restrict__ G,
                                             float* __restrict__ Dt,
                                             float* __restrict__ Gd,
                                             float* __restrict__ HB) {
  __shared__ float smem[2 * DIM * 128];  // 64 KiB
  const int b = blockIdx.x;
  if (b < 256) {
    const int i0 = (b >> 4) * 64, j0 = (b & 15) * 64;
    float(*sA)[65] = (float(*)[65])smem;
    float(*sB)[65] = (float(*)[65])(smem + DIM * 65);
    for (int t = threadIdx.x; t < DIM * 16; t += 256) {
      int d = t >> 4, c4 = (t & 15) * 4;
      *reinterpret_cast<float4*>(&sA[d][c4]) =
          *reinterpret_cast<const float4*>(&D[(size_t)d * NATOM + i0 + c4]);
      *reinterpret_cast<float4*>(&sB[d][c4]) =
          *reinterpret_cast<const float4*>(&D[(size_t)d * NATOM + j0 + c4]);
    }
    __syncthreads();
    const int ty = (threadIdx.x >> 4) * 4;
    const int tx = (threadIdx.x & 15) * 4;
    double acc[4][4];
#pragma unroll
    for (int ii = 0; ii < 4; ++ii)
#pragma unroll
      for (int jj = 0; jj < 4; ++jj) acc[ii][jj] = 0.0;
    for (int d = 0; d < DIM; ++d) {
      float a[4], bb[4];
#pragma unroll
      for (int ii = 0; ii < 4; ++ii) a[ii] = sA[d][ty + ii];
#pragma unroll
      for (int jj = 0; jj < 4; ++jj) bb[jj] = sB[d][tx + jj];
#pragma unroll
      for (int ii = 0; ii < 4; ++ii)
#pragma unroll
        for (int jj = 0; jj < 4; ++jj)
          acc[ii][jj] += (double)a[ii] * (double)bb[jj];
    }
#pragma unroll
    for (int ii = 0; ii < 4; ++ii)
#pragma unroll
      for (int jj = 0; jj < 4; ++jj) {
        const int k1 = i0 + ty + ii, k2 = j0 + tx + jj;
        float g = (float)acc[ii][jj];
        if (k1 == k2) {
          g += 1e-4f;
          Gd[k1] = g;
        }
        G[(size_t)k1 * NATOM + k2] = g;
      }
  } else if (b < 320) {
    const int base = (b - 256) * 1024 + threadIdx.x * 4;
    float4 v = *reinterpret_cast<const float4*>(&D[base]);
    const float vv[4] = {v.x, v.y, v.z, v.w};
#pragma unroll
    for (int e = 0; e < 4; ++e) {
      int idx = base + e;
      Dt[(size_t)(idx & (NATOM - 1)) * DIM + (idx >> 10)] = vv[e];
    }
  } else {
    const int bx = b - 320;
    const int n0 = (bx & 127) * 128, k0 = (bx >> 7) * 128;
    float(*sX)[128] = (float(*)[128])smem;
    float(*sD)[128] = (float(*)[128])(smem + DIM * 128);
    for (int i = threadIdx.x; i < DIM * 32; i += 256) {
      int d = i >> 5, c4 = (i & 31) * 4;
      *reinterpret_cast<float4*>(&sX[d][c4]) =
          *reinterpret_cast<const float4*>(&X[(size_t)d * NPIX + n0 + c4]);
      *reinterpret_cast<float4*>(&sD[d][c4]) =
          *reinterpret_cast<const float4*>(&D[(size_t)d * NATOM + k0 + c4]);
    }
    __syncthreads();
    const int nl = (threadIdx.x & 15) * 8;
    const int kl = (threadIdx.x >> 4) * 8;
    float acc[8][8];
#pragma unroll
    for (int i = 0; i < 8; ++i)
#pragma unroll
      for (int j = 0; j < 8; ++j) acc[i][j] = 0.f;
#pragma unroll 4
    for (int d = 0; d < DIM; ++d) {
      float xv[8], dv[8];
      *reinterpret_cast<float4*>(&xv[0]) = *reinterpret_cast<float4*>(&sX[d][nl]);
      *reinterpret_cast<float4*>(&xv[4]) = *reinterpret_cast<float4*>(&sX[d][nl + 4]);
      *reinterpret_cast<float4*>(&dv[0]) = *reinterpret_cast<float4*>(&sD[d][kl]);
      *reinterpret_cast<float4*>(&dv[4]) = *reinterpret_cast<float4*>(&sD[d][kl + 4]);
#pragma unroll
      for (int i = 0; i < 8; ++i)
#pragma unroll
        for (int j = 0; j < 8; ++j) acc[i][j] = fmaf(xv[i], dv[j], acc[i][j]);
    }
#pragma unroll
    for (int i = 0; i < 8; ++i)
#pragma unroll
      for (int j = 0; j < 2; ++j)
        *reinterpret_cast<float4*>(
            &HB[(size_t)(n0 + nl + i) * NATOM + k0 + kl + j * 4]) =
            *reinterpret_cast<float4*>(&acc[i][j * 4]);
  }
}

// ---------------------------------------------------------------------------
// DPP wave64 max-reduce (VALU latency, no LDS). HW-verified (rounds 6-19).
// ---------------------------------------------------------------------------
template <int CTRL>
__device__ __forceinline__ float dpp_fmax(float x) {
  int s = __builtin_amdgcn_update_dpp(__float_as_int(x), __float_as_int(x),
                                      CTRL, 0xf, 0xf, false);
  return fmaxf(x, __int_as_float(s));
}
__device__ __forceinline__ float wave_max_bcast(float x) {
  x = dpp_fmax<0x111>(x);  // row_shr:1
  x = dpp_fmax<0x112>(x);  // row_shr:2
  x = dpp_fmax<0x114>(x);  // row_shr:4
  x = dpp_fmax<0x118>(x);  // row_shr:8
  x = dpp_fmax<0x142>(x);  // row_bcast:15
  x = dpp_fmax<0x143>(x);  // row_bcast:31
  return __int_as_float(__builtin_amdgcn_readlane(__float_as_int(x), 63));
}

// force a wave-uniform fp32 value into SGPR allocation (identity on values)
__device__ __forceinline__ float sgprf(float x) {
  return __int_as_float(__builtin_amdgcn_readfirstlane(__float_as_int(x)));
}

// ---------------------------------------------------------------------------
// Batched OMP via Batch-OMP residual recurrence (R15/R16-verified math),
// R16 configuration (pins + __launch_bounds__(64,3)) PLUS the W-column
// identity: the step-s Cholesky column w = L^{-1} G_I[:,bk] equals
// wr[:, bk] — already in registers of the owning lane. The serial scalar
// triangular recurrence and its 7 column loads are replaced by a uniform
// switch(bj) register select + readlane(bl). Bit-identical by induction
// (same fmaf sequence, same inputs, same order).
// ONE WAVE PER PIXEL. Lane owns atoms k = lane*16+j.
// Argmax: exact f32 DPP wave-max; 4 parallel descending-j chains + umin
// tree; ballot+ffs (== np.argmax first occurrence). NaN-poison h.
// hbs/diag via wave-uniform scalar loads. Solver state in SGPRs (sgprf).
// ---------------------------------------------------------------------------
template <bool DTW>
__global__ __launch_bounds__(64, 3) void k_omp(const float* __restrict__ HB,
                                               const float* __restrict__ Dt,
                                               const float* __restrict__ D,
                                               const float* __restrict__ G,
                                               const float* __restrict__ Gd,
                                               float* __restrict__ out) {
  const int lane = threadIdx.x & 63;
  const int lane16 = lane * 16;
  const int n = __builtin_amdgcn_readfirstlane(blockIdx.x);

  float h[16];  // residual correlations; starts as h_bar, updated in place
#pragma unroll
  for (int q = 0; q < 4; ++q) {
    float4 v = *reinterpret_cast<const float4*>(
        &HB[(size_t)n * NATOM + lane16 + q * 4]);
    h[q * 4 + 0] = v.x; h[q * 4 + 1] = v.y;
    h[q * 4 + 2] = v.z; h[q * 4 + 3] = v.w;
  }
#pragma unroll
  for (int j = 0; j < 16; ++j) asm volatile("" : "+v"(h[j]));

  int selI[SPAR];            // wave-uniform -> SGPRs
  float wr[SPAR - 1][16];    // wr[t][j] = (L^{-1} G_I)[t][lane16+j], pinned
  float Lm[SPAR][SPAR], invL[SPAR], ysel[SPAR];  // uniform -> SGPR via sgprf

#pragma unroll 8
  for (int s = 0; s < SPAR; ++s) {
    // ---- argmax over |h| (NaN-poisoned slots lose: fmaxf ignores NaN) ----
    float m0 = fmaxf(fmaxf(fabsf(h[0]), fabsf(h[1])), fabsf(h[2]));
    float m1 = fmaxf(fmaxf(fabsf(h[3]), fabsf(h[4])), fabsf(h[5]));
    float m2 = fmaxf(fmaxf(fabsf(h[6]), fabsf(h[7])), fabsf(h[8]));
    float m3 = fmaxf(fmaxf(fabsf(h[9]), fabsf(h[10])), fabsf(h[11]));
    float m4 = fmaxf(fmaxf(fabsf(h[12]), fabsf(h[13])), fabsf(h[14]));
    float m5 = fabsf(h[15]);
    const float M = wave_max_bcast(
        fmaxf(fmaxf(fmaxf(m0, m1), m2), fmaxf(fmaxf(m3, m4), m5)));
    // ---- in-lane first match: 4 parallel descending chains + umin tree ----
    unsigned c0 = NATOM, c1 = NATOM, c2 = NATOM, c3 = NATOM;
#pragma unroll
    for (int j = 3; j >= 0; --j) {
      c0 = (fabsf(h[j]) == M) ? (unsigned)(lane16 + j) : c0;
      c1 = (fabsf(h[4 + j]) == M) ? (unsigned)(lane16 + 4 + j) : c1;
      c2 = (fabsf(h[8 + j]) == M) ? (unsigned)(lane16 + 8 + j) : c2;
      c3 = (fabsf(h[12 + j]) == M) ? (unsigned)(lane16 + 12 + j) : c3;
    }
    unsigned ca = c0 < c1 ? c0 : c1;
    unsigned cb = c2 < c3 ? c2 : c3;
    unsigned cand = ca < cb ? ca : cb;
    unsigned long long bal = __ballot(cand != (unsigned)NATOM);
    const int fl = __ffsll(bal) - 1;
    const int bk = __builtin_amdgcn_readlane((int)cand, fl);  // wave-uniform
    selI[s] = bk;
    const int bl = bk >> 4, bj = bk & 15;

    // poison the selected slot: loses every future argmax (NaN semantics)
#pragma unroll
    for (int j = 0; j < 16; ++j)
      if (j == bj && lane == bl) h[j] = __builtin_nanf("");

    // issue G-row fetch early; its waitcnt lands after the solve below
    float g[16];
    if (s < SPAR - 1) {
#pragma unroll
      for (int q = 0; q < 4; ++q) {
        float4 rv = *reinterpret_cast<const float4*>(
            &G[(size_t)bk * NATOM + lane16 + q * 4]);
        g[q * 4 + 0] = rv.x; g[q * 4 + 1] = rv.y;
        g[q * 4 + 2] = rv.z; g[q * 4 + 3] = rv.w;
      }
    }

    // ---- w = L^{-1} G_I[:,bk] == wr[:, bk] (owner lane bl, slot bj) ----
    // Uniform switch over bj selects the column from registers; readlane
    // broadcasts from the owning lane. Bit-identical to the scalar chain.
    float wsel[SPAR - 1];
#pragma unroll
    for (int j = 0; j < 16; ++j)
      if (j == bj) {  // wave-uniform condition -> scalar branch
#pragma unroll
        for (int i = 0; i < SPAR - 1; ++i)
          if (i < s) wsel[i] = wr[i][j];
      }
    const float hbs = HB[(size_t)n * NATOM + bk];  // uniform scalar load
    const float diag = Gd[bk];
    float sq = 0.f;
#pragma unroll
    for (int i = 0; i < SPAR - 1; ++i)
      if (i < s) {
        const float wi = __int_as_float(
            __builtin_amdgcn_readlane(__float_as_int(wsel[i]), bl));
        sq += wi * wi;
        Lm[s][i] = wi;  // already uniform (readlane)
      }
    float cc = diag - sq;
    if (cc < 1e-6f) cc = 1e-6f;  // jnp.clip(..., CHOL_EPS)
    invL[s] = sgprf(1.0f / sqrtf(cc));

    // ---- y_s (incremental forward solve; earlier entries stable) ----
    {
      float a = hbs;
#pragma unroll
      for (int t = 0; t < SPAR; ++t)
        if (t < s) a = fmaf(-Lm[s][t], ysel[t], a);
      ysel[s] = sgprf(a * invL[s]);
    }

    // ---- build wr_s = (g - sum_t Lm[s][t]*wr_t) * invL[s]; h -= y_s*wr_s --
    if (s < SPAR - 1) {
#pragma unroll
      for (int j = 0; j < 16; ++j) {
        float a = g[j];
#pragma unroll
        for (int t = 0; t < SPAR - 1; ++t)
          if (t < s) a = fmaf(-Lm[s][t], wr[t][j], a);
        float v = a * invL[s];
        wr[s][j] = v;
        h[j] = fmaf(-ysel[s], v, h[j]);
      }
#pragma unroll
      for (int j = 0; j < 16; ++j) asm volatile("" : "+v"(wr[s][j]));
    }
  }

  // ---- final backward solve L^T c = y (op-identical to prior rounds) ----
  float coefF[SPAR];
#pragma unroll
  for (int i = SPAR - 1; i >= 0; --i) {
    float a = ysel[i];
#pragma unroll
    for (int t = 0; t < SPAR; ++t)
      if (t > i) a = fmaf(-Lm[t][i], coefF[t], a);
    coefF[i] = a * invL[i];
  }

  // ---- outputs: recon [n][64], I [n][8], coeffs [n][8] ----
  double r = 0.0;
#pragma unroll
  for (int i = 0; i < SPAR; ++i) {
    float dv = DTW ? Dt[(size_t)selI[i] * DIM + lane]
                   : D[(size_t)lane * NATOM + selI[i]];
    r += (double)coefF[i] * (double)dv;
  }
  out[(size_t)n * DIM + lane] = (float)r;

  float fi = 0.f, fc = 0.f;
#pragma unroll
  for (int i = 0; i < SPAR; ++i)
    if (lane == i) { fi = (float)selI[i]; fc = coefF[i]; }
  if (lane < SPAR) {
    out[(size_t)NPIX * DIM + (size_t)n * SPAR + lane] = fi;
    out[(size_t)NPIX * DIM + (size_t)NPIX * SPAR + (size_t)n * SPAR + lane] = fc;
  }
}

// ---------------------------------------------------------------------------
// Fallback single-wave OMP (tiny-workspace path; R10 kernel). Unchanged.
// ---------------------------------------------------------------------------
__global__ __launch_bounds__(64) void k_omp_fb(const float* __restrict__ X,
                                               const float* __restrict__ D,
                                               const float* __restrict__ G,
                                               const float* __restrict__ Gd,
                                               float* __restrict__ out) {
  const int lane = threadIdx.x & 63;
  const int lane16 = lane * 16;
  const int n = __builtin_amdgcn_readfirstlane(blockIdx.x);

  float hb[16];
  {
    double a[16];
#pragma unroll
    for (int j = 0; j < 16; ++j) a[j] = 0.0;
    for (int d = 0; d < DIM; ++d) {
      float xd = X[(size_t)d * NPIX + n];
#pragma unroll
      for (int j = 0; j < 16; ++j)
        a[j] += (double)xd * (double)D[(size_t)d * NATOM + lane16 + j];
    }
#pragma unroll
    for (int j = 0; j < 16; ++j) hb[j] = (float)a[j];
  }
#pragma unroll
  for (int j = 0; j < 16; ++j) asm volatile("" : "+v"(hb[j]));

  int selI[SPAR];
  float rows[SPAR - 1][16];
  float Lm[SPAR][SPAR], invL[SPAR], ysel[SPAR], coefF[SPAR];

#pragma unroll 8
  for (int s = 0; s < SPAR; ++s) {
    float h[16];
#pragma unroll
    for (int j = 0; j < 16; ++j) {
      float hv = hb[j];
#pragma unroll
      for (int i = 0; i < SPAR - 1; ++i)
        if (i < s) hv = fmaf(-coefF[i], rows[i][j], hv);
      h[j] = hv;
    }
    float m0 = fmaxf(fmaxf(fmaxf(fabsf(h[0]), fabsf(h[1])), fabsf(h[2])), fabsf(h[3]));
    float m1 = fmaxf(fmaxf(fmaxf(fabsf(h[4]), fabsf(h[5])), fabsf(h[6])), fabsf(h[7]));
    float m2 = fmaxf(fmaxf(fmaxf(fabsf(h[8]), fabsf(h[9])), fabsf(h[10])), fabsf(h[11]));
    float m3 = fmaxf(fmaxf(fmaxf(fabsf(h[12]), fabsf(h[13])), fabsf(h[14])), fabsf(h[15]));
    const float M = wave_max_bcast(fmaxf(fmaxf(m0, m1), fmaxf(m2, m3)));
    unsigned cand = NATOM;
#pragma unroll
    for (int j = 15; j >= 0; --j)
      cand = (fabsf(h[j]) == M) ? (unsigned)(lane16 + j) : cand;
    unsigned long long bal = __ballot(cand != (unsigned)NATOM);
    const int fl = __ffsll(bal) - 1;
    const int bk = __builtin_amdgcn_readlane((int)cand, fl);
    selI[s] = bk;
    const int bl = bk >> 4, bj = bk & 15;

    float v = 0.f;
#pragma unroll
    for (int j = 0; j < 16; ++j)
      if (j == bj) v = hb[j];
    const float hbs =
        __int_as_float(__builtin_amdgcn_readlane(__float_as_int(v), bl));

#pragma unroll
    for (int j = 0; j < 16; ++j)
      if (j == bj && lane == bl) hb[j] = __builtin_nanf("");

    if (s < SPAR - 1) {
#pragma unroll
      for (int q = 0; q < 4; ++q) {
        float4 rv = *reinterpret_cast<const float4*>(
            &G[(size_t)bk * NATOM + lane16 + q * 4]);
        rows[s][q * 4 + 0] = rv.x; rows[s][q * 4 + 1] = rv.y;
        rows[s][q * 4 + 2] = rv.z; rows[s][q * 4 + 3] = rv.w;
      }
    }

    const float diag = Gd[bk];
    float w[SPAR];
    float sq = 0.f;
#pragma unroll
    for (int i = 0; i < SPAR; ++i)
      if (i < s) {
        float a = G[(size_t)selI[i] * NATOM + bk];
#pragma unroll
        for (int t = 0; t < SPAR; ++t)
          if (t < i) a = fmaf(-Lm[i][t], w[t], a);
        w[i] = a * invL[i];
        sq += w[i] * w[i];
        Lm[s][i] = w[i];
      }
    float cc = diag - sq;
    if (cc < 1e-6f) cc = 1e-6f;
    invL[s] = 1.0f / sqrtf(cc);
    {
      float a = hbs;
#pragma unroll
      for (int t = 0; t < SPAR; ++t)
        if (t < s) a = fmaf(-Lm[s][t], ysel[t], a);
      ysel[s] = a * invL[s];
    }
#pragma unroll
    for (int i = SPAR - 1; i >= 0; --i)
      if (i <= s) {
        float a = ysel[i];
#pragma unroll
        for (int t = 0; t < SPAR; ++t)
          if (t > i && t <= s) a = fmaf(-Lm[t][i], coefF[t], a);
        coefF[i] = a * invL[i];
      }
    if (s < SPAR - 1) {
#pragma unroll
      for (int j = 0; j < 16; ++j) asm volatile("" : "+v"(rows[s][j]));
    }
  }

  double r = 0.0;
#pragma unroll
  for (int i = 0; i < SPAR; ++i)
    r += (double)coefF[i] * (double)D[(size_t)lane * NATOM + selI[i]];
  out[(size_t)n * DIM + lane] = (float)r;

  float fi = 0.f, fc = 0.f;
#pragma unroll
  for (int i = 0; i < SPAR; ++i)
    if (lane == i) { fi = (float)selI[i]; fc = coefF[i]; }
  if (lane < SPAR) {
    out[(size_t)NPIX * DIM + (size_t)n * SPAR + lane] = fi;
    out[(size_t)NPIX * DIM + (size_t)NPIX * SPAR + (size_t)n * SPAR + lane] = fc;
  }
}

__global__ __launch_bounds__(256) void k_gram(const float* __restrict__ D,
                                              float* __restrict__ G,
                                              float* __restrict__ Gd) {
  int k1 = blockIdx.x;
  __shared__ float d1[DIM];
  if (threadIdx.x < DIM) d1[threadIdx.x] = D[(size_t)threadIdx.x * NATOM + k1];
  __syncthreads();
  for (int k2 = threadIdx.x; k2 < NATOM; k2 += 256) {
    double acc = 0.0;
#pragma unroll
    for (int d = 0; d < DIM; ++d)
      acc += (double)d1[d] * (double)D[(size_t)d * NATOM + k2];
    float g = (float)acc;
    if (k2 == k1) {
      g += 1e-4f;
      Gd[k1] = g;
    }
    G[(size_t)k1 * NATOM + k2] = g;
  }
}

extern "C" void kernel_launch(void* const* d_in, const int* in_sizes, int n_in,
                              void* d_out, int out_size, void* d_ws,
                              size_t ws_size, hipStream_t stream) {
  const float* X = (const float*)d_in[0];  // [64, 16384]
  const float* D = (const float*)d_in[1];  // [64, 1024]
  float* out = (float*)d_out;              // [recon | I | coeffs] as fp32
  float* G = (float*)d_ws;                 // 4 MB
  float* Dt = G + (size_t)NATOM * NATOM;   // 256 KB
  float* Gd = Dt + (size_t)NATOM * DIM;    // 4 KB
  float* HB = Gd + NATOM;                  // 64 MB
  const size_t needFull =
      ((size_t)NATOM * NATOM + (size_t)NATOM * DIM + NATOM +
       (size_t)NPIX * NATOM) * sizeof(float);

  if (ws_size >= needFull) {
    k_pre<<<dim3(1344), dim3(256), 0, stream>>>(X, D, G, Dt, Gd, HB);
    k_omp<true><<<dim3(NPIX), dim3(64), 0, stream>>>(HB, Dt, nullptr, G, Gd, out);
  } else {
    k_gram<<<dim3(NATOM), dim3(256), 0, stream>>>(D, G, Gd);
    k_omp_fb<<<dim3(NPIX), dim3(64), 0, stream>>>(X, D, G, Gd, out);
  }
}